// Round 1
// baseline (709.429 us; speedup 1.0000x reference)
//
#include <hip/hip_runtime.h>

#define SS 512
#define NPARTS 11
#define NB 4
#define FEAT (9*126*126)   // 142884

// ws layout (floats)
#define H1SZ (4*7*254*254)       // 1806448
#define H2SZ (4*FEAT)            // 571536
#define OFF_H1 0
#define OFF_H2 (OFF_H1 + H1SZ)
#define OFF_PART (OFF_H2 + H2SZ)      // [32][8][4] = 1024
#define OFF_THETA (OFF_PART + 1024)   // [4][66] = 264

// ---------------- conv1 (5x5, 4->7) + relu + maxpool2 ----------------
// in: x channel-last [B, 6144, 512, 4] -> float4 per pixel; chunk 0 = rows 0..511
// out: h1 [4][7][254][254]
__global__ __launch_bounds__(256) void conv1_kernel(
    const float4* __restrict__ x4,
    const float* __restrict__ w,      // [7][4][5][5]
    const float* __restrict__ bias,   // [7]
    float* __restrict__ h1) {
  __shared__ float ws[700];
  int tid = threadIdx.x;
  for (int i = tid; i < 700; i += 256) ws[i] = w[i];
  __syncthreads();
  int b = blockIdx.y;
  int idx = blockIdx.x * 256 + tid;
  if (idx >= 254 * 254) return;
  int py = idx / 254, px = idx % 254;
  const float4* img = x4 + (size_t)b * 6144 * 512;
  float best[7];
#pragma unroll
  for (int k = 0; k < 7; k++) best[k] = -1e30f;
  for (int pos = 0; pos < 4; pos++) {
    int oy = 2 * py + (pos >> 1), ox = 2 * px + (pos & 1);
    float acc[7];
#pragma unroll
    for (int k = 0; k < 7; k++) acc[k] = bias[k];
    for (int dy = 0; dy < 5; dy++) {
      const float4* row = img + (size_t)(oy + dy) * 512 + ox;
#pragma unroll
      for (int dx = 0; dx < 5; dx++) {
        float4 v = row[dx];
        int wi = dy * 5 + dx;
#pragma unroll
        for (int k = 0; k < 7; k++) {
          const float* wk = &ws[k * 100 + wi];
          acc[k] += v.x * wk[0] + v.y * wk[25] + v.z * wk[50] + v.w * wk[75];
        }
      }
    }
#pragma unroll
    for (int k = 0; k < 7; k++) best[k] = fmaxf(best[k], acc[k]);
  }
#pragma unroll
  for (int k = 0; k < 7; k++)
    h1[(((size_t)b * 7 + k) * 254 + py) * 254 + px] = fmaxf(best[k], 0.0f);
}

// ---------------- conv2 (3x3, 7->9) + relu + maxpool2 ----------------
// in: h1 [4][7][254][254], out: h2 [4][9][126][126]
__global__ __launch_bounds__(256) void conv2_kernel(
    const float* __restrict__ h1,
    const float* __restrict__ w,      // [9][7][3][3]
    const float* __restrict__ bias,   // [9]
    float* __restrict__ h2) {
  __shared__ float ws[567];
  int tid = threadIdx.x;
  for (int i = tid; i < 567; i += 256) ws[i] = w[i];
  __syncthreads();
  int b = blockIdx.y;
  int idx = blockIdx.x * 256 + tid;
  if (idx >= 126 * 126) return;
  int py = idx / 126, px = idx % 126;
  float best[9];
#pragma unroll
  for (int k = 0; k < 9; k++) best[k] = -1e30f;
  for (int pos = 0; pos < 4; pos++) {
    int oy = 2 * py + (pos >> 1), ox = 2 * px + (pos & 1);
    float acc[9];
#pragma unroll
    for (int k = 0; k < 9; k++) acc[k] = bias[k];
    for (int c = 0; c < 7; c++) {
      const float* in = h1 + (((size_t)b * 7 + c) * 254 + oy) * 254 + ox;
#pragma unroll
      for (int dy = 0; dy < 3; dy++) {
#pragma unroll
        for (int dx = 0; dx < 3; dx++) {
          float v = in[dy * 254 + dx];
          int wi = c * 9 + dy * 3 + dx;
#pragma unroll
          for (int k = 0; k < 9; k++) acc[k] += v * ws[k * 63 + wi];
        }
      }
    }
#pragma unroll
    for (int k = 0; k < 9; k++) best[k] = fmaxf(best[k], acc[k]);
  }
#pragma unroll
  for (int k = 0; k < 9; k++)
    h2[(((size_t)b * 9 + k) * 126 + py) * 126 + px] = fmaxf(best[k], 0.0f);
}

// ---------------- fc1 split-K partials ----------------
// grid (32, 8): partials[(j*8+s)*4 + b]
__global__ __launch_bounds__(256) void fc1_kernel(
    const float* __restrict__ h2,    // [4][FEAT]
    const float* __restrict__ w,     // [32][FEAT]
    float* __restrict__ partials) {
  int j = blockIdx.x;
  int s = blockIdx.y;
  int tid = threadIdx.x;
  const int CH = (FEAT + 7) / 8;
  int f0 = s * CH;
  int f1 = f0 + CH; if (f1 > FEAT) f1 = FEAT;
  float a0 = 0.f, a1 = 0.f, a2 = 0.f, a3 = 0.f;
  const float* wj = w + (size_t)j * FEAT;
  for (int f = f0 + tid; f < f1; f += 256) {
    float wv = wj[f];
    a0 += wv * h2[f];
    a1 += wv * h2[FEAT + f];
    a2 += wv * h2[2 * FEAT + f];
    a3 += wv * h2[3 * FEAT + f];
  }
  __shared__ float4 red[256];
  red[tid] = make_float4(a0, a1, a2, a3);
  __syncthreads();
  for (int off = 128; off > 0; off >>= 1) {
    if (tid < off) {
      float4 o = red[tid + off];
      red[tid].x += o.x; red[tid].y += o.y; red[tid].z += o.z; red[tid].w += o.w;
    }
    __syncthreads();
  }
  if (tid == 0) {
    float4 r = red[0];
    float* p = partials + ((size_t)j * 8 + s) * 4;
    p[0] = r.x; p[1] = r.y; p[2] = r.z; p[3] = r.w;
  }
}

// ---------------- head: finish fc1, fc2, fc3, side outputs ----------------
__global__ __launch_bounds__(256) void head_kernel(
    const float* __restrict__ partials,
    const float* __restrict__ b1,     // [32]
    const float* __restrict__ w2,     // [33][32]
    const float* __restrict__ b2,     // [33]
    const float* __restrict__ w3,     // [66][33]
    const float* __restrict__ b3,     // [66]
    float* __restrict__ theta_out,    // [4][66]
    float* __restrict__ out_tail) {   // close_to_eye(176) + translations(88)
  __shared__ float h32[128];  // [4][32]
  __shared__ float h33[132];  // [4][33]
  __shared__ float th[264];   // [4][66]
  int tid = threadIdx.x;
  for (int t = tid; t < 128; t += 256) {
    int b = t >> 5, j = t & 31;
    float sacc = b1[j];
    for (int k = 0; k < 8; k++) sacc += partials[((size_t)j * 8 + k) * 4 + b];
    h32[b * 32 + j] = fmaxf(sacc, 0.0f);
  }
  __syncthreads();
  for (int t = tid; t < 132; t += 256) {
    int b = t / 33, j2 = t % 33;
    float sacc = b2[j2];
    for (int j = 0; j < 32; j++) sacc += h32[b * 32 + j] * w2[j2 * 32 + j];
    h33[b * 33 + j2] = fmaxf(sacc, 0.0f);
  }
  __syncthreads();
  for (int t = tid; t < 264; t += 256) {
    int b = t / 66, u = t % 66;
    float sacc = b3[u];
    for (int j2 = 0; j2 < 33; j2++) sacc += h33[b * 33 + j2] * w3[u * 33 + j2];
    th[t] = sacc;
    theta_out[t] = sacc;
  }
  __syncthreads();
  // close_to_eye: [b][p][i][k] = sum_j Rm[i][j]*Rm[k][j]
  for (int t = tid; t < 176; t += 256) {
    int b = t / 44, r = t % 44, p = r / 4, ik = r % 4;
    int i = ik >> 1, k = ik & 1;
    const float* T = &th[b * 66 + p * 6];
    out_tail[t] = T[i * 3 + 0] * T[k * 3 + 0] + T[i * 3 + 1] * T[k * 3 + 1];
  }
  // translations
  for (int t = tid; t < 88; t += 256) {
    int b = t / 22, r = t % 22, p = r / 2, i = r % 2;
    out_tail[176 + t] = th[b * 66 + p * 6 + i * 3 + 2];
  }
}

// ---------------- warp + alpha composite ----------------
// parts[i][b][c][y][x] = x[b, (i+1)*512 + y, x, c] (float4 per pixel)
// out stack: [B][4][512][512]
__global__ __launch_bounds__(256) void warp_kernel(
    const float4* __restrict__ x4,
    const float* __restrict__ theta,  // [4][66]
    float* __restrict__ out) {
  int tid = threadIdx.x;
  int gid = blockIdx.x * 256 + tid;
  int b = gid >> 18;
  int y = (gid >> 9) & 511;
  int x = gid & 511;
  __shared__ float th[66];
  if (tid < 66) th[tid] = theta[b * 66 + tid];
  __syncthreads();
  float xs = (2 * x + 1) * (1.0f / 512.0f) - 1.0f;
  float ys = (2 * y + 1) * (1.0f / 512.0f) - 1.0f;
  const float4* img0 = x4 + (size_t)b * 6144 * 512;
  float4 stack = make_float4(0.f, 0.f, 0.f, 0.f);
#pragma unroll 1
  for (int i = 0; i < NPARTS; i++) {
    const float* T = &th[i * 6];
    float gx = T[0] * xs + T[1] * ys + T[2];
    float gy = T[3] * xs + T[4] * ys + T[5];
    float ix = ((gx + 1.0f) * 512.0f - 1.0f) * 0.5f;
    float iy = ((gy + 1.0f) * 512.0f - 1.0f) * 0.5f;
    float x0 = floorf(ix), y0 = floorf(iy);
    float wx = ix - x0, wy = iy - y0;
    int x0i = min(max((int)x0, 0), 511);
    int x1i = min(max((int)x0 + 1, 0), 511);
    int y0i = min(max((int)y0, 0), 511);
    int y1i = min(max((int)y0 + 1, 0), 511);
    const float4* img = img0 + (size_t)(i + 1) * 512 * 512;
    float4 v00 = img[y0i * 512 + x0i];
    float4 v01 = img[y0i * 512 + x1i];
    float4 v10 = img[y1i * 512 + x0i];
    float4 v11 = img[y1i * 512 + x1i];
    float w00 = (1.f - wx) * (1.f - wy), w01 = wx * (1.f - wy);
    float w10 = (1.f - wx) * wy, w11 = wx * wy;
    float4 val;
    val.x = v00.x * w00 + v01.x * w01 + v10.x * w10 + v11.x * w11;
    val.y = v00.y * w00 + v01.y * w01 + v10.y * w10 + v11.y * w11;
    val.z = v00.z * w00 + v01.z * w01 + v10.z * w10 + v11.z * w11;
    val.w = v00.w * w00 + v01.w * w01 + v10.w * w10 + v11.w * w11;
    if (i == 0) {
      stack = val;
    } else {
      float a = fminf(fmaxf(val.w, 0.0f), 1.0f);
      stack.x = fminf(fmaxf(stack.x - 2.f * a, -1.f), 1.f);
      stack.y = fminf(fmaxf(stack.y - 2.f * a, -1.f), 1.f);
      stack.z = fminf(fmaxf(stack.z - 2.f * a, -1.f), 1.f);
      stack.w = fminf(fmaxf(stack.w - 2.f * a, -1.f), 1.f);
      stack.x = fminf(fmaxf(stack.x + val.x + 1.f, -1.f), 1.f);
      stack.y = fminf(fmaxf(stack.y + val.y + 1.f, -1.f), 1.f);
      stack.z = fminf(fmaxf(stack.z + val.z + 1.f, -1.f), 1.f);
      stack.w = fminf(fmaxf(stack.w + val.w + 1.f, -1.f), 1.f);
    }
  }
  size_t obase = (size_t)b * 4 * 262144 + (size_t)y * 512 + x;
  out[obase] = stack.x;
  out[obase + 262144] = stack.y;
  out[obase + 2 * 262144] = stack.z;
  out[obase + 3 * 262144] = stack.w;
}

extern "C" void kernel_launch(void* const* d_in, const int* in_sizes, int n_in,
                              void* d_out, int out_size, void* d_ws, size_t ws_size,
                              hipStream_t stream) {
  const float4* x4 = (const float4*)d_in[0];
  const float* conv1_w = (const float*)d_in[1];
  const float* conv1_b = (const float*)d_in[2];
  const float* conv2_w = (const float*)d_in[3];
  const float* conv2_b = (const float*)d_in[4];
  const float* fc1_w = (const float*)d_in[5];
  const float* fc1_b = (const float*)d_in[6];
  const float* fc2_w = (const float*)d_in[7];
  const float* fc2_b = (const float*)d_in[8];
  const float* fc3_w = (const float*)d_in[9];
  const float* fc3_b = (const float*)d_in[10];
  float* ws = (float*)d_ws;
  float* out = (float*)d_out;

  conv1_kernel<<<dim3(253, 4), 256, 0, stream>>>(x4, conv1_w, conv1_b, ws + OFF_H1);
  conv2_kernel<<<dim3(63, 4), 256, 0, stream>>>(ws + OFF_H1, conv2_w, conv2_b, ws + OFF_H2);
  fc1_kernel<<<dim3(32, 8), 256, 0, stream>>>(ws + OFF_H2, fc1_w, ws + OFF_PART);
  head_kernel<<<1, 256, 0, stream>>>(ws + OFF_PART, fc1_b, fc2_w, fc2_b, fc3_w, fc3_b,
                                     ws + OFF_THETA, out + 4194304);
  warp_kernel<<<4096, 256, 0, stream>>>(x4, ws + OFF_THETA, out);
}

// Round 2
// 184.391 us; speedup vs baseline: 3.8474x; 3.8474x over previous
//
#include <hip/hip_runtime.h>

#define SS 512
#define NPARTS 11
#define NB 4
#define FEAT (9*126*126)   // 142884

// ws layout (floats)
#define H1SZ (4*7*254*254)       // 1806448
#define H2SZ (4*FEAT)            // 571536
#define OFF_H1 0
#define OFF_H2 (OFF_H1 + H1SZ)
#define OFF_PART (OFF_H2 + H2SZ)      // [32][8][4] = 1024
#define OFF_THETA (OFF_PART + 1024)   // [4][66] = 264

// ---------------- conv1 (5x5, 4->7) + relu + maxpool2, LDS-tiled ----------------
// block: 16x16 pooled outputs; needs 36x36 float4 input halo.
// grid: (16*16, 4)
__global__ __launch_bounds__(256) void conv1_kernel(
    const float4* __restrict__ x4,
    const float* __restrict__ w,      // [7][4][5][5]
    const float* __restrict__ bias,   // [7]
    float* __restrict__ h1) {
  __shared__ float4 tile[36 * 37];    // padded row stride
  __shared__ float ws[700];
  int tid = threadIdx.x;
  int b = blockIdx.y;
  int tileid = blockIdx.x;
  int by = tileid >> 4, bx = tileid & 15;
  int y0 = by * 32, x0 = bx * 32;     // input-space tile origin

  for (int i = tid; i < 700; i += 256) ws[i] = w[i];
  const float4* img = x4 + (size_t)b * 6144 * 512;
  for (int i = tid; i < 36 * 36; i += 256) {
    int r = i / 36, c = i % 36;
    int gy = y0 + r, gx = x0 + c;
    float4 v = make_float4(0.f, 0.f, 0.f, 0.f);
    if (gy < 512 && gx < 512) v = img[(size_t)gy * 512 + gx];
    tile[r * 37 + c] = v;
  }
  __syncthreads();

  int ty = tid >> 4, tx = tid & 15;   // local pooled coords
  float acc[4][7];
#pragma unroll
  for (int p = 0; p < 4; p++)
#pragma unroll
    for (int k = 0; k < 7; k++) acc[p][k] = bias[k];

#pragma unroll
  for (int dy = 0; dy < 5; dy++) {
    const float4* r0 = &tile[(2 * ty + dy) * 37 + 2 * tx];
    const float4* r1 = r0 + 37;
    float4 a0[6], a1[6];
#pragma unroll
    for (int j = 0; j < 6; j++) { a0[j] = r0[j]; a1[j] = r1[j]; }
#pragma unroll
    for (int dx = 0; dx < 5; dx++) {
      float4 v00 = a0[dx], v01 = a0[dx + 1];
      float4 v10 = a1[dx], v11 = a1[dx + 1];
#pragma unroll
      for (int k = 0; k < 7; k++) {
        const float* wk = &ws[k * 100 + dy * 5 + dx];
        float w0 = wk[0], w1 = wk[25], w2 = wk[50], w3 = wk[75];
        acc[0][k] += v00.x * w0 + v00.y * w1 + v00.z * w2 + v00.w * w3;
        acc[1][k] += v01.x * w0 + v01.y * w1 + v01.z * w2 + v01.w * w3;
        acc[2][k] += v10.x * w0 + v10.y * w1 + v10.z * w2 + v10.w * w3;
        acc[3][k] += v11.x * w0 + v11.y * w1 + v11.z * w2 + v11.w * w3;
      }
    }
  }

  int py = by * 16 + ty, px = bx * 16 + tx;
  if (py < 254 && px < 254) {
#pragma unroll
    for (int k = 0; k < 7; k++) {
      float m = fmaxf(fmaxf(acc[0][k], acc[1][k]), fmaxf(acc[2][k], acc[3][k]));
      h1[(((size_t)b * 7 + k) * 254 + py) * 254 + px] = fmaxf(m, 0.0f);
    }
  }
}

// ---------------- conv2 (3x3, 7->9) + relu + maxpool2, LDS-tiled ----------------
// block: 16x16 pooled outputs; 34x34 halo per channel, 7 channels.
// grid: (8*8, 4)
__global__ __launch_bounds__(256) void conv2_kernel(
    const float* __restrict__ h1,     // [4][7][254][254]
    const float* __restrict__ w,      // [9][7][3][3]
    const float* __restrict__ bias,   // [9]
    float* __restrict__ h2) {
  __shared__ float tile[7 * 34 * 35]; // padded
  __shared__ float ws[567];
  int tid = threadIdx.x;
  int b = blockIdx.y;
  int tileid = blockIdx.x;
  int by = tileid >> 3, bx = tileid & 7;
  int y0 = by * 32, x0 = bx * 32;

  for (int i = tid; i < 567; i += 256) ws[i] = w[i];
  for (int i = tid; i < 7 * 34 * 34; i += 256) {
    int c = i / (34 * 34), rem = i % (34 * 34);
    int r = rem / 34, col = rem % 34;
    int gy = y0 + r, gx = x0 + col;
    float v = 0.f;
    if (gy < 254 && gx < 254)
      v = h1[(((size_t)b * 7 + c) * 254 + gy) * 254 + gx];
    tile[(c * 34 + r) * 35 + col] = v;
  }
  __syncthreads();

  int ty = tid >> 4, tx = tid & 15;
  float acc[4][9];
#pragma unroll
  for (int p = 0; p < 4; p++)
#pragma unroll
    for (int k = 0; k < 9; k++) acc[p][k] = bias[k];

  for (int c = 0; c < 7; c++) {
#pragma unroll
    for (int dy = 0; dy < 3; dy++) {
      const float* r0 = &tile[(c * 34 + 2 * ty + dy) * 35 + 2 * tx];
      const float* r1 = r0 + 35;
      float a0[4], a1[4];
#pragma unroll
      for (int j = 0; j < 4; j++) { a0[j] = r0[j]; a1[j] = r1[j]; }
#pragma unroll
      for (int dx = 0; dx < 3; dx++) {
#pragma unroll
        for (int k = 0; k < 9; k++) {
          float wv = ws[k * 63 + c * 9 + dy * 3 + dx];
          acc[0][k] += a0[dx] * wv;
          acc[1][k] += a0[dx + 1] * wv;
          acc[2][k] += a1[dx] * wv;
          acc[3][k] += a1[dx + 1] * wv;
        }
      }
    }
  }

  int py = by * 16 + ty, px = bx * 16 + tx;
  if (py < 126 && px < 126) {
#pragma unroll
    for (int k = 0; k < 9; k++) {
      float m = fmaxf(fmaxf(acc[0][k], acc[1][k]), fmaxf(acc[2][k], acc[3][k]));
      h2[(((size_t)b * 9 + k) * 126 + py) * 126 + px] = fmaxf(m, 0.0f);
    }
  }
}

// ---------------- fc1 split-K partials ----------------
__global__ __launch_bounds__(256) void fc1_kernel(
    const float* __restrict__ h2,    // [4][FEAT]
    const float* __restrict__ w,     // [32][FEAT]
    float* __restrict__ partials) {
  int j = blockIdx.x;
  int s = blockIdx.y;
  int tid = threadIdx.x;
  const int CH = (FEAT + 7) / 8;
  int f0 = s * CH;
  int f1 = f0 + CH; if (f1 > FEAT) f1 = FEAT;
  float a0 = 0.f, a1 = 0.f, a2 = 0.f, a3 = 0.f;
  const float* wj = w + (size_t)j * FEAT;
  for (int f = f0 + tid; f < f1; f += 256) {
    float wv = wj[f];
    a0 += wv * h2[f];
    a1 += wv * h2[FEAT + f];
    a2 += wv * h2[2 * FEAT + f];
    a3 += wv * h2[3 * FEAT + f];
  }
  __shared__ float4 red[256];
  red[tid] = make_float4(a0, a1, a2, a3);
  __syncthreads();
  for (int off = 128; off > 0; off >>= 1) {
    if (tid < off) {
      float4 o = red[tid + off];
      red[tid].x += o.x; red[tid].y += o.y; red[tid].z += o.z; red[tid].w += o.w;
    }
    __syncthreads();
  }
  if (tid == 0) {
    float4 r = red[0];
    float* p = partials + ((size_t)j * 8 + s) * 4;
    p[0] = r.x; p[1] = r.y; p[2] = r.z; p[3] = r.w;
  }
}

// ---------------- head: finish fc1, fc2, fc3, side outputs ----------------
__global__ __launch_bounds__(256) void head_kernel(
    const float* __restrict__ partials,
    const float* __restrict__ b1,     // [32]
    const float* __restrict__ w2,     // [33][32]
    const float* __restrict__ b2,     // [33]
    const float* __restrict__ w3,     // [66][33]
    const float* __restrict__ b3,     // [66]
    float* __restrict__ theta_out,    // [4][66]
    float* __restrict__ out_tail) {   // close_to_eye(176) + translations(88)
  __shared__ float h32[128];  // [4][32]
  __shared__ float h33[132];  // [4][33]
  __shared__ float th[264];   // [4][66]
  int tid = threadIdx.x;
  for (int t = tid; t < 128; t += 256) {
    int b = t >> 5, j = t & 31;
    float sacc = b1[j];
    for (int k = 0; k < 8; k++) sacc += partials[((size_t)j * 8 + k) * 4 + b];
    h32[b * 32 + j] = fmaxf(sacc, 0.0f);
  }
  __syncthreads();
  for (int t = tid; t < 132; t += 256) {
    int b = t / 33, j2 = t % 33;
    float sacc = b2[j2];
    for (int j = 0; j < 32; j++) sacc += h32[b * 32 + j] * w2[j2 * 32 + j];
    h33[b * 33 + j2] = fmaxf(sacc, 0.0f);
  }
  __syncthreads();
  for (int t = tid; t < 264; t += 256) {
    int b = t / 66, u = t % 66;
    float sacc = b3[u];
    for (int j2 = 0; j2 < 33; j2++) sacc += h33[b * 33 + j2] * w3[u * 33 + j2];
    th[t] = sacc;
    theta_out[t] = sacc;
  }
  __syncthreads();
  for (int t = tid; t < 176; t += 256) {
    int b = t / 44, r = t % 44, p = r / 4, ik = r % 4;
    int i = ik >> 1, k = ik & 1;
    const float* T = &th[b * 66 + p * 6];
    out_tail[t] = T[i * 3 + 0] * T[k * 3 + 0] + T[i * 3 + 1] * T[k * 3 + 1];
  }
  for (int t = tid; t < 88; t += 256) {
    int b = t / 22, r = t % 22, p = r / 2, i = r % 2;
    out_tail[176 + t] = th[b * 66 + p * 6 + i * 3 + 2];
  }
}

// ---------------- warp + alpha composite ----------------
__global__ __launch_bounds__(256) void warp_kernel(
    const float4* __restrict__ x4,
    const float* __restrict__ theta,  // [4][66]
    float* __restrict__ out) {
  int tid = threadIdx.x;
  int gid = blockIdx.x * 256 + tid;
  int b = gid >> 18;
  int y = (gid >> 9) & 511;
  int x = gid & 511;
  __shared__ float th[66];
  if (tid < 66) th[tid] = theta[b * 66 + tid];
  __syncthreads();
  float xs = (2 * x + 1) * (1.0f / 512.0f) - 1.0f;
  float ys = (2 * y + 1) * (1.0f / 512.0f) - 1.0f;
  const float4* img0 = x4 + (size_t)b * 6144 * 512;
  float4 stack = make_float4(0.f, 0.f, 0.f, 0.f);
#pragma unroll 1
  for (int i = 0; i < NPARTS; i++) {
    const float* T = &th[i * 6];
    float gx = T[0] * xs + T[1] * ys + T[2];
    float gy = T[3] * xs + T[4] * ys + T[5];
    float ix = ((gx + 1.0f) * 512.0f - 1.0f) * 0.5f;
    float iy = ((gy + 1.0f) * 512.0f - 1.0f) * 0.5f;
    float x0 = floorf(ix), y0 = floorf(iy);
    float wx = ix - x0, wy = iy - y0;
    int x0i = min(max((int)x0, 0), 511);
    int x1i = min(max((int)x0 + 1, 0), 511);
    int y0i = min(max((int)y0, 0), 511);
    int y1i = min(max((int)y0 + 1, 0), 511);
    const float4* img = img0 + (size_t)(i + 1) * 512 * 512;
    float4 v00 = img[y0i * 512 + x0i];
    float4 v01 = img[y0i * 512 + x1i];
    float4 v10 = img[y1i * 512 + x0i];
    float4 v11 = img[y1i * 512 + x1i];
    float w00 = (1.f - wx) * (1.f - wy), w01 = wx * (1.f - wy);
    float w10 = (1.f - wx) * wy, w11 = wx * wy;
    float4 val;
    val.x = v00.x * w00 + v01.x * w01 + v10.x * w10 + v11.x * w11;
    val.y = v00.y * w00 + v01.y * w01 + v10.y * w10 + v11.y * w11;
    val.z = v00.z * w00 + v01.z * w01 + v10.z * w10 + v11.z * w11;
    val.w = v00.w * w00 + v01.w * w01 + v10.w * w10 + v11.w * w11;
    if (i == 0) {
      stack = val;
    } else {
      float a = fminf(fmaxf(val.w, 0.0f), 1.0f);
      stack.x = fminf(fmaxf(stack.x - 2.f * a, -1.f), 1.f);
      stack.y = fminf(fmaxf(stack.y - 2.f * a, -1.f), 1.f);
      stack.z = fminf(fmaxf(stack.z - 2.f * a, -1.f), 1.f);
      stack.w = fminf(fmaxf(stack.w - 2.f * a, -1.f), 1.f);
      stack.x = fminf(fmaxf(stack.x + val.x + 1.f, -1.f), 1.f);
      stack.y = fminf(fmaxf(stack.y + val.y + 1.f, -1.f), 1.f);
      stack.z = fminf(fmaxf(stack.z + val.z + 1.f, -1.f), 1.f);
      stack.w = fminf(fmaxf(stack.w + val.w + 1.f, -1.f), 1.f);
    }
  }
  size_t obase = (size_t)b * 4 * 262144 + (size_t)y * 512 + x;
  out[obase] = stack.x;
  out[obase + 262144] = stack.y;
  out[obase + 2 * 262144] = stack.z;
  out[obase + 3 * 262144] = stack.w;
}

extern "C" void kernel_launch(void* const* d_in, const int* in_sizes, int n_in,
                              void* d_out, int out_size, void* d_ws, size_t ws_size,
                              hipStream_t stream) {
  const float4* x4 = (const float4*)d_in[0];
  const float* conv1_w = (const float*)d_in[1];
  const float* conv1_b = (const float*)d_in[2];
  const float* conv2_w = (const float*)d_in[3];
  const float* conv2_b = (const float*)d_in[4];
  const float* fc1_w = (const float*)d_in[5];
  const float* fc1_b = (const float*)d_in[6];
  const float* fc2_w = (const float*)d_in[7];
  const float* fc2_b = (const float*)d_in[8];
  const float* fc3_w = (const float*)d_in[9];
  const float* fc3_b = (const float*)d_in[10];
  float* ws = (float*)d_ws;
  float* out = (float*)d_out;

  conv1_kernel<<<dim3(256, 4), 256, 0, stream>>>(x4, conv1_w, conv1_b, ws + OFF_H1);
  conv2_kernel<<<dim3(64, 4), 256, 0, stream>>>(ws + OFF_H1, conv2_w, conv2_b, ws + OFF_H2);
  fc1_kernel<<<dim3(32, 8), 256, 0, stream>>>(ws + OFF_H2, fc1_w, ws + OFF_PART);
  head_kernel<<<1, 256, 0, stream>>>(ws + OFF_PART, fc1_b, fc2_w, fc2_b, fc3_w, fc3_b,
                                     ws + OFF_THETA, out + 4194304);
  warp_kernel<<<4096, 256, 0, stream>>>(x4, ws + OFF_THETA, out);
}

// Round 3
// 140.136 us; speedup vs baseline: 5.0624x; 1.3158x over previous
//
#include <hip/hip_runtime.h>

#define SS 512
#define NPARTS 11
#define NB 4
#define FEAT (9*126*126)   // 142884

// ws layout (floats)
#define H1SZ (4*7*254*254)       // 1806448
#define H2SZ (4*FEAT)            // 571536
#define OFF_H1 0
#define OFF_H2 (OFF_H1 + H1SZ)
#define OFF_PART (OFF_H2 + H2SZ)      // [32][8][4] = 1024
#define OFF_THETA (OFF_PART + 1024)   // [4][66] = 264

// ---------------- conv1 (5x5, 4->7) + relu + maxpool2, LDS-tiled ----------------
// block: 16x16 pooled outputs; 36x36 float4 input halo in LDS.
// weights read DIRECTLY from global (wave-uniform, compile-time offsets -> s_load).
__global__ __launch_bounds__(256) void conv1_kernel(
    const float4* __restrict__ x4,
    const float* __restrict__ w,      // [7][4][5][5]
    const float* __restrict__ bias,   // [7]
    float* __restrict__ h1) {
  __shared__ float4 tile[36 * 37];    // padded row stride
  int tid = threadIdx.x;
  int b = blockIdx.y;
  int by = blockIdx.x >> 4, bx = blockIdx.x & 15;
  int y0 = by * 32, x0 = bx * 32;     // input-space tile origin

  const float4* img = x4 + (size_t)b * 6144 * 512;
  for (int i = tid; i < 36 * 36; i += 256) {
    int r = i / 36, c = i % 36;
    int gy = y0 + r, gx = x0 + c;
    float4 v = make_float4(0.f, 0.f, 0.f, 0.f);
    if (gy < 512 && gx < 512) v = img[(size_t)gy * 512 + gx];
    tile[r * 37 + c] = v;
  }
  __syncthreads();

  int ty = tid >> 4, tx = tid & 15;   // local pooled coords
  float acc[4][7];
#pragma unroll
  for (int p = 0; p < 4; p++)
#pragma unroll
    for (int k = 0; k < 7; k++) acc[p][k] = bias[k];

#pragma unroll
  for (int dy = 0; dy < 5; dy++) {
    const float4* r0 = &tile[(2 * ty + dy) * 37 + 2 * tx];
    const float4* r1 = r0 + 37;
    float4 a0[6], a1[6];
#pragma unroll
    for (int j = 0; j < 6; j++) { a0[j] = r0[j]; a1[j] = r1[j]; }
#pragma unroll
    for (int dx = 0; dx < 5; dx++) {
      float4 v00 = a0[dx], v01 = a0[dx + 1];
      float4 v10 = a1[dx], v11 = a1[dx + 1];
#pragma unroll
      for (int k = 0; k < 7; k++) {
        const float* wk = &w[k * 100 + dy * 5 + dx];   // uniform -> scalar load
        float w0 = wk[0], w1 = wk[25], w2 = wk[50], w3 = wk[75];
        acc[0][k] += v00.x * w0 + v00.y * w1 + v00.z * w2 + v00.w * w3;
        acc[1][k] += v01.x * w0 + v01.y * w1 + v01.z * w2 + v01.w * w3;
        acc[2][k] += v10.x * w0 + v10.y * w1 + v10.z * w2 + v10.w * w3;
        acc[3][k] += v11.x * w0 + v11.y * w1 + v11.z * w2 + v11.w * w3;
      }
    }
  }

  int py = by * 16 + ty, px = bx * 16 + tx;
  if (py < 254 && px < 254) {
#pragma unroll
    for (int k = 0; k < 7; k++) {
      float m = fmaxf(fmaxf(acc[0][k], acc[1][k]), fmaxf(acc[2][k], acc[3][k]));
      h1[(((size_t)b * 7 + k) * 254 + py) * 254 + px] = fmaxf(m, 0.0f);
    }
  }
}

// ---------------- conv2 (3x3, 7->9) + relu + maxpool2, LDS-tiled ----------------
__global__ __launch_bounds__(256) void conv2_kernel(
    const float* __restrict__ h1,     // [4][7][254][254]
    const float* __restrict__ w,      // [9][7][3][3]
    const float* __restrict__ bias,   // [9]
    float* __restrict__ h2) {
  __shared__ float tile[7 * 34 * 35]; // padded
  int tid = threadIdx.x;
  int b = blockIdx.y;
  int by = blockIdx.x >> 3, bx = blockIdx.x & 7;
  int y0 = by * 32, x0 = bx * 32;

  for (int i = tid; i < 7 * 34 * 34; i += 256) {
    int c = i / (34 * 34), rem = i % (34 * 34);
    int r = rem / 34, col = rem % 34;
    int gy = y0 + r, gx = x0 + col;
    float v = 0.f;
    if (gy < 254 && gx < 254)
      v = h1[(((size_t)b * 7 + c) * 254 + gy) * 254 + gx];
    tile[(c * 34 + r) * 35 + col] = v;
  }
  __syncthreads();

  int ty = tid >> 4, tx = tid & 15;
  float acc[4][9];
#pragma unroll
  for (int p = 0; p < 4; p++)
#pragma unroll
    for (int k = 0; k < 9; k++) acc[p][k] = bias[k];

  for (int c = 0; c < 7; c++) {
#pragma unroll
    for (int dy = 0; dy < 3; dy++) {
      const float* r0 = &tile[(c * 34 + 2 * ty + dy) * 35 + 2 * tx];
      const float* r1 = r0 + 35;
      float a0[4], a1[4];
#pragma unroll
      for (int j = 0; j < 4; j++) { a0[j] = r0[j]; a1[j] = r1[j]; }
#pragma unroll
      for (int dx = 0; dx < 3; dx++) {
#pragma unroll
        for (int k = 0; k < 9; k++) {
          float wv = w[k * 63 + c * 9 + dy * 3 + dx];  // uniform -> scalar load
          acc[0][k] += a0[dx] * wv;
          acc[1][k] += a0[dx + 1] * wv;
          acc[2][k] += a1[dx] * wv;
          acc[3][k] += a1[dx + 1] * wv;
        }
      }
    }
  }

  int py = by * 16 + ty, px = bx * 16 + tx;
  if (py < 126 && px < 126) {
#pragma unroll
    for (int k = 0; k < 9; k++) {
      float m = fmaxf(fmaxf(acc[0][k], acc[1][k]), fmaxf(acc[2][k], acc[3][k]));
      h2[(((size_t)b * 9 + k) * 126 + py) * 126 + px] = fmaxf(m, 0.0f);
    }
  }
}

// ---------------- fc1 split-K partials ----------------
__global__ __launch_bounds__(256) void fc1_kernel(
    const float* __restrict__ h2,    // [4][FEAT]
    const float* __restrict__ w,     // [32][FEAT]
    float* __restrict__ partials) {
  int j = blockIdx.x;
  int s = blockIdx.y;
  int tid = threadIdx.x;
  const int CH = (FEAT + 7) / 8;
  int f0 = s * CH;
  int f1 = f0 + CH; if (f1 > FEAT) f1 = FEAT;
  float a0 = 0.f, a1 = 0.f, a2 = 0.f, a3 = 0.f;
  const float* wj = w + (size_t)j * FEAT;
  for (int f = f0 + tid; f < f1; f += 256) {
    float wv = wj[f];
    a0 += wv * h2[f];
    a1 += wv * h2[FEAT + f];
    a2 += wv * h2[2 * FEAT + f];
    a3 += wv * h2[3 * FEAT + f];
  }
  __shared__ float4 red[256];
  red[tid] = make_float4(a0, a1, a2, a3);
  __syncthreads();
  for (int off = 128; off > 0; off >>= 1) {
    if (tid < off) {
      float4 o = red[tid + off];
      red[tid].x += o.x; red[tid].y += o.y; red[tid].z += o.z; red[tid].w += o.w;
    }
    __syncthreads();
  }
  if (tid == 0) {
    float4 r = red[0];
    float* p = partials + ((size_t)j * 8 + s) * 4;
    p[0] = r.x; p[1] = r.y; p[2] = r.z; p[3] = r.w;
  }
}

// ---------------- head: finish fc1, fc2, fc3, side outputs ----------------
__global__ __launch_bounds__(256) void head_kernel(
    const float* __restrict__ partials,
    const float* __restrict__ b1,     // [32]
    const float* __restrict__ w2,     // [33][32]
    const float* __restrict__ b2,     // [33]
    const float* __restrict__ w3,     // [66][33]
    const float* __restrict__ b3,     // [66]
    float* __restrict__ theta_out,    // [4][66]
    float* __restrict__ out_tail) {   // close_to_eye(176) + translations(88)
  __shared__ float h32[128];  // [4][32]
  __shared__ float h33[132];  // [4][33]
  __shared__ float th[264];   // [4][66]
  int tid = threadIdx.x;
  for (int t = tid; t < 128; t += 256) {
    int b = t >> 5, j = t & 31;
    float sacc = b1[j];
    for (int k = 0; k < 8; k++) sacc += partials[((size_t)j * 8 + k) * 4 + b];
    h32[b * 32 + j] = fmaxf(sacc, 0.0f);
  }
  __syncthreads();
  for (int t = tid; t < 132; t += 256) {
    int b = t / 33, j2 = t % 33;
    float sacc = b2[j2];
    for (int j = 0; j < 32; j++) sacc += h32[b * 32 + j] * w2[j2 * 32 + j];
    h33[b * 33 + j2] = fmaxf(sacc, 0.0f);
  }
  __syncthreads();
  for (int t = tid; t < 264; t += 256) {
    int b = t / 66, u = t % 66;
    float sacc = b3[u];
    for (int j2 = 0; j2 < 33; j2++) sacc += h33[b * 33 + j2] * w3[u * 33 + j2];
    th[t] = sacc;
    theta_out[t] = sacc;
  }
  __syncthreads();
  for (int t = tid; t < 176; t += 256) {
    int b = t / 44, r = t % 44, p = r / 4, ik = r % 4;
    int i = ik >> 1, k = ik & 1;
    const float* T = &th[b * 66 + p * 6];
    out_tail[t] = T[i * 3 + 0] * T[k * 3 + 0] + T[i * 3 + 1] * T[k * 3 + 1];
  }
  for (int t = tid; t < 88; t += 256) {
    int b = t / 22, r = t % 22, p = r / 2, i = r % 2;
    out_tail[176 + t] = th[b * 66 + p * 6 + i * 3 + 2];
  }
}

// ---------------- warp + alpha composite, 32x8 output tiles ----------------
__global__ __launch_bounds__(256) void warp_kernel(
    const float4* __restrict__ x4,
    const float* __restrict__ theta,  // [4][66]
    float* __restrict__ out) {
  int tid = threadIdx.x;
  int b = blockIdx.x >> 10;
  int t = blockIdx.x & 1023;
  int ty = t >> 4, tx = t & 15;       // 64 y-tiles x 16 x-tiles
  int y = ty * 8 + (tid >> 5);
  int x = tx * 32 + (tid & 31);
  __shared__ float th[66];
  if (tid < 66) th[tid] = theta[b * 66 + tid];
  __syncthreads();
  float xs = (2 * x + 1) * (1.0f / 512.0f) - 1.0f;
  float ys = (2 * y + 1) * (1.0f / 512.0f) - 1.0f;
  const float4* img0 = x4 + (size_t)b * 6144 * 512;
  float4 stack = make_float4(0.f, 0.f, 0.f, 0.f);
#pragma unroll 1
  for (int i = 0; i < NPARTS; i++) {
    const float* T = &th[i * 6];
    float gx = T[0] * xs + T[1] * ys + T[2];
    float gy = T[3] * xs + T[4] * ys + T[5];
    float ix = ((gx + 1.0f) * 512.0f - 1.0f) * 0.5f;
    float iy = ((gy + 1.0f) * 512.0f - 1.0f) * 0.5f;
    float x0 = floorf(ix), y0 = floorf(iy);
    float wx = ix - x0, wy = iy - y0;
    int x0i = min(max((int)x0, 0), 511);
    int x1i = min(max((int)x0 + 1, 0), 511);
    int y0i = min(max((int)y0, 0), 511);
    int y1i = min(max((int)y0 + 1, 0), 511);
    const float4* img = img0 + (size_t)(i + 1) * 512 * 512;
    float4 v00 = img[y0i * 512 + x0i];
    float4 v01 = img[y0i * 512 + x1i];
    float4 v10 = img[y1i * 512 + x0i];
    float4 v11 = img[y1i * 512 + x1i];
    float w00 = (1.f - wx) * (1.f - wy), w01 = wx * (1.f - wy);
    float w10 = (1.f - wx) * wy, w11 = wx * wy;
    float4 val;
    val.x = v00.x * w00 + v01.x * w01 + v10.x * w10 + v11.x * w11;
    val.y = v00.y * w00 + v01.y * w01 + v10.y * w10 + v11.y * w11;
    val.z = v00.z * w00 + v01.z * w01 + v10.z * w10 + v11.z * w11;
    val.w = v00.w * w00 + v01.w * w01 + v10.w * w10 + v11.w * w11;
    if (i == 0) {
      stack = val;
    } else {
      float a = fminf(fmaxf(val.w, 0.0f), 1.0f);
      stack.x = fminf(fmaxf(stack.x - 2.f * a, -1.f), 1.f);
      stack.y = fminf(fmaxf(stack.y - 2.f * a, -1.f), 1.f);
      stack.z = fminf(fmaxf(stack.z - 2.f * a, -1.f), 1.f);
      stack.w = fminf(fmaxf(stack.w - 2.f * a, -1.f), 1.f);
      stack.x = fminf(fmaxf(stack.x + val.x + 1.f, -1.f), 1.f);
      stack.y = fminf(fmaxf(stack.y + val.y + 1.f, -1.f), 1.f);
      stack.z = fminf(fmaxf(stack.z + val.z + 1.f, -1.f), 1.f);
      stack.w = fminf(fmaxf(stack.w + val.w + 1.f, -1.f), 1.f);
    }
  }
  size_t obase = (size_t)b * 4 * 262144 + (size_t)y * 512 + x;
  out[obase] = stack.x;
  out[obase + 262144] = stack.y;
  out[obase + 2 * 262144] = stack.z;
  out[obase + 3 * 262144] = stack.w;
}

extern "C" void kernel_launch(void* const* d_in, const int* in_sizes, int n_in,
                              void* d_out, int out_size, void* d_ws, size_t ws_size,
                              hipStream_t stream) {
  const float4* x4 = (const float4*)d_in[0];
  const float* conv1_w = (const float*)d_in[1];
  const float* conv1_b = (const float*)d_in[2];
  const float* conv2_w = (const float*)d_in[3];
  const float* conv2_b = (const float*)d_in[4];
  const float* fc1_w = (const float*)d_in[5];
  const float* fc1_b = (const float*)d_in[6];
  const float* fc2_w = (const float*)d_in[7];
  const float* fc2_b = (const float*)d_in[8];
  const float* fc3_w = (const float*)d_in[9];
  const float* fc3_b = (const float*)d_in[10];
  float* ws = (float*)d_ws;
  float* out = (float*)d_out;

  conv1_kernel<<<dim3(256, 4), 256, 0, stream>>>(x4, conv1_w, conv1_b, ws + OFF_H1);
  conv2_kernel<<<dim3(64, 4), 256, 0, stream>>>(ws + OFF_H1, conv2_w, conv2_b, ws + OFF_H2);
  fc1_kernel<<<dim3(32, 8), 256, 0, stream>>>(ws + OFF_H2, fc1_w, ws + OFF_PART);
  head_kernel<<<1, 256, 0, stream>>>(ws + OFF_PART, fc1_b, fc2_w, fc2_b, fc3_w, fc3_b,
                                     ws + OFF_THETA, out + 4194304);
  warp_kernel<<<4096, 256, 0, stream>>>(x4, ws + OFF_THETA, out);
}

// Round 4
// 139.082 us; speedup vs baseline: 5.1008x; 1.0076x over previous
//
#include <hip/hip_runtime.h>

#define SS 512
#define NPARTS 11
#define NB 4
#define FEAT (9*126*126)   // 142884

// ws layout (floats)
#define H1SZ (4*7*254*254)       // 1806448
#define H2SZ (4*FEAT)            // 571536
#define OFF_H1 0
#define OFF_H2 (OFF_H1 + H1SZ)
#define OFF_PART (OFF_H2 + H2SZ)      // [32][8][4] = 1024
#define OFF_THETA (OFF_PART + 1024)   // [4][66] = 264

// ---------------- conv1 (5x5, 4->7) + relu + maxpool2, LDS-tiled ----------------
__global__ __launch_bounds__(256) void conv1_kernel(
    const float4* __restrict__ x4,
    const float* __restrict__ w,      // [7][4][5][5]
    const float* __restrict__ bias,   // [7]
    float* __restrict__ h1) {
  __shared__ float4 tile[36 * 37];    // padded row stride
  int tid = threadIdx.x;
  int b = blockIdx.y;
  int by = blockIdx.x >> 4, bx = blockIdx.x & 15;
  int y0 = by * 32, x0 = bx * 32;

  const float4* img = x4 + (size_t)b * 6144 * 512;
  for (int i = tid; i < 36 * 36; i += 256) {
    int r = i / 36, c = i % 36;
    int gy = y0 + r, gx = x0 + c;
    float4 v = make_float4(0.f, 0.f, 0.f, 0.f);
    if (gy < 512 && gx < 512) v = img[(size_t)gy * 512 + gx];
    tile[r * 37 + c] = v;
  }
  __syncthreads();

  int ty = tid >> 4, tx = tid & 15;
  float acc[4][7];
#pragma unroll
  for (int p = 0; p < 4; p++)
#pragma unroll
    for (int k = 0; k < 7; k++) acc[p][k] = bias[k];

#pragma unroll
  for (int dy = 0; dy < 5; dy++) {
    const float4* r0 = &tile[(2 * ty + dy) * 37 + 2 * tx];
    const float4* r1 = r0 + 37;
    float4 a0[6], a1[6];
#pragma unroll
    for (int j = 0; j < 6; j++) { a0[j] = r0[j]; a1[j] = r1[j]; }
#pragma unroll
    for (int dx = 0; dx < 5; dx++) {
      float4 v00 = a0[dx], v01 = a0[dx + 1];
      float4 v10 = a1[dx], v11 = a1[dx + 1];
#pragma unroll
      for (int k = 0; k < 7; k++) {
        const float* wk = &w[k * 100 + dy * 5 + dx];   // uniform -> scalar load
        float w0 = wk[0], w1 = wk[25], w2 = wk[50], w3 = wk[75];
        acc[0][k] += v00.x * w0 + v00.y * w1 + v00.z * w2 + v00.w * w3;
        acc[1][k] += v01.x * w0 + v01.y * w1 + v01.z * w2 + v01.w * w3;
        acc[2][k] += v10.x * w0 + v10.y * w1 + v10.z * w2 + v10.w * w3;
        acc[3][k] += v11.x * w0 + v11.y * w1 + v11.z * w2 + v11.w * w3;
      }
    }
  }

  int py = by * 16 + ty, px = bx * 16 + tx;
  if (py < 254 && px < 254) {
#pragma unroll
    for (int k = 0; k < 7; k++) {
      float m = fmaxf(fmaxf(acc[0][k], acc[1][k]), fmaxf(acc[2][k], acc[3][k]));
      h1[(((size_t)b * 7 + k) * 254 + py) * 254 + px] = fmaxf(m, 0.0f);
    }
  }
}

// ---------------- conv2 (3x3, 7->9) + relu + maxpool2, LDS-tiled ----------------
__global__ __launch_bounds__(256) void conv2_kernel(
    const float* __restrict__ h1,     // [4][7][254][254]
    const float* __restrict__ w,      // [9][7][3][3]
    const float* __restrict__ bias,   // [9]
    float* __restrict__ h2) {
  __shared__ float tile[7 * 34 * 35];
  int tid = threadIdx.x;
  int b = blockIdx.y;
  int by = blockIdx.x >> 3, bx = blockIdx.x & 7;
  int y0 = by * 32, x0 = bx * 32;

  for (int i = tid; i < 7 * 34 * 34; i += 256) {
    int c = i / (34 * 34), rem = i % (34 * 34);
    int r = rem / 34, col = rem % 34;
    int gy = y0 + r, gx = x0 + col;
    float v = 0.f;
    if (gy < 254 && gx < 254)
      v = h1[(((size_t)b * 7 + c) * 254 + gy) * 254 + gx];
    tile[(c * 34 + r) * 35 + col] = v;
  }
  __syncthreads();

  int ty = tid >> 4, tx = tid & 15;
  float acc[4][9];
#pragma unroll
  for (int p = 0; p < 4; p++)
#pragma unroll
    for (int k = 0; k < 9; k++) acc[p][k] = bias[k];

  for (int c = 0; c < 7; c++) {
#pragma unroll
    for (int dy = 0; dy < 3; dy++) {
      const float* r0 = &tile[(c * 34 + 2 * ty + dy) * 35 + 2 * tx];
      const float* r1 = r0 + 35;
      float a0[4], a1[4];
#pragma unroll
      for (int j = 0; j < 4; j++) { a0[j] = r0[j]; a1[j] = r1[j]; }
#pragma unroll
      for (int dx = 0; dx < 3; dx++) {
#pragma unroll
        for (int k = 0; k < 9; k++) {
          float wv = w[k * 63 + c * 9 + dy * 3 + dx];  // uniform -> scalar load
          acc[0][k] += a0[dx] * wv;
          acc[1][k] += a0[dx + 1] * wv;
          acc[2][k] += a1[dx] * wv;
          acc[3][k] += a1[dx + 1] * wv;
        }
      }
    }
  }

  int py = by * 16 + ty, px = bx * 16 + tx;
  if (py < 126 && px < 126) {
#pragma unroll
    for (int k = 0; k < 9; k++) {
      float m = fmaxf(fmaxf(acc[0][k], acc[1][k]), fmaxf(acc[2][k], acc[3][k]));
      h2[(((size_t)b * 9 + k) * 126 + py) * 126 + px] = fmaxf(m, 0.0f);
    }
  }
}

// ---------------- fc1 split-K partials ----------------
__global__ __launch_bounds__(256) void fc1_kernel(
    const float* __restrict__ h2,    // [4][FEAT]
    const float* __restrict__ w,     // [32][FEAT]
    float* __restrict__ partials) {
  int j = blockIdx.x;
  int s = blockIdx.y;
  int tid = threadIdx.x;
  const int CH = (FEAT + 7) / 8;
  int f0 = s * CH;
  int f1 = f0 + CH; if (f1 > FEAT) f1 = FEAT;
  float a0 = 0.f, a1 = 0.f, a2 = 0.f, a3 = 0.f;
  const float* wj = w + (size_t)j * FEAT;
  for (int f = f0 + tid; f < f1; f += 256) {
    float wv = wj[f];
    a0 += wv * h2[f];
    a1 += wv * h2[FEAT + f];
    a2 += wv * h2[2 * FEAT + f];
    a3 += wv * h2[3 * FEAT + f];
  }
  __shared__ float4 red[256];
  red[tid] = make_float4(a0, a1, a2, a3);
  __syncthreads();
  for (int off = 128; off > 0; off >>= 1) {
    if (tid < off) {
      float4 o = red[tid + off];
      red[tid].x += o.x; red[tid].y += o.y; red[tid].z += o.z; red[tid].w += o.w;
    }
    __syncthreads();
  }
  if (tid == 0) {
    float4 r = red[0];
    float* p = partials + ((size_t)j * 8 + s) * 4;
    p[0] = r.x; p[1] = r.y; p[2] = r.z; p[3] = r.w;
  }
}

// ---------------- head: finish fc1, fc2, fc3, side outputs ----------------
__global__ __launch_bounds__(256) void head_kernel(
    const float* __restrict__ partials,
    const float* __restrict__ b1,     // [32]
    const float* __restrict__ w2,     // [33][32]
    const float* __restrict__ b2,     // [33]
    const float* __restrict__ w3,     // [66][33]
    const float* __restrict__ b3,     // [66]
    float* __restrict__ theta_out,    // [4][66]
    float* __restrict__ out_tail) {   // close_to_eye(176) + translations(88)
  __shared__ float h32[128];
  __shared__ float h33[132];
  __shared__ float th[264];
  int tid = threadIdx.x;
  for (int t = tid; t < 128; t += 256) {
    int b = t >> 5, j = t & 31;
    float sacc = b1[j];
    for (int k = 0; k < 8; k++) sacc += partials[((size_t)j * 8 + k) * 4 + b];
    h32[b * 32 + j] = fmaxf(sacc, 0.0f);
  }
  __syncthreads();
  for (int t = tid; t < 132; t += 256) {
    int b = t / 33, j2 = t % 33;
    float sacc = b2[j2];
    for (int j = 0; j < 32; j++) sacc += h32[b * 32 + j] * w2[j2 * 32 + j];
    h33[b * 33 + j2] = fmaxf(sacc, 0.0f);
  }
  __syncthreads();
  for (int t = tid; t < 264; t += 256) {
    int b = t / 66, u = t % 66;
    float sacc = b3[u];
    for (int j2 = 0; j2 < 33; j2++) sacc += h33[b * 33 + j2] * w3[u * 33 + j2];
    th[t] = sacc;
    theta_out[t] = sacc;
  }
  __syncthreads();
  for (int t = tid; t < 176; t += 256) {
    int b = t / 44, r = t % 44, p = r / 4, ik = r % 4;
    int i = ik >> 1, k = ik & 1;
    const float* T = &th[b * 66 + p * 6];
    out_tail[t] = T[i * 3 + 0] * T[k * 3 + 0] + T[i * 3 + 1] * T[k * 3 + 1];
  }
  for (int t = tid; t < 88; t += 256) {
    int b = t / 22, r = t % 22, p = r / 2, i = r % 2;
    out_tail[176 + t] = th[b * 66 + p * 6 + i * 3 + 2];
  }
}

// ---------------- warp + alpha composite ----------------
// block = 16x16 output tile; wave = 16x4 patch; XCD-chunked block swizzle.
__global__ __launch_bounds__(256) void warp_kernel(
    const float4* __restrict__ x4,
    const float* __restrict__ theta,  // [4][66]
    float* __restrict__ out) {
  int bid = blockIdx.x;
  int swz = (bid & 7) * 512 + (bid >> 3);   // 4096 blocks -> 8 chunks of 512
  int b = swz >> 10;
  int t = swz & 1023;
  int ty = t >> 5, tx = t & 31;             // 32x32 tiles of 16x16
  int tid = threadIdx.x;
  int wv = tid >> 6, l = tid & 63;
  int y = ty * 16 + wv * 4 + (l >> 4);
  int x = tx * 16 + (l & 15);

  __shared__ float th[66];
  if (tid < 66) th[tid] = theta[b * 66 + tid];
  __syncthreads();

  const float4* img0 = x4 + (size_t)b * 6144 * 512;
  float fx = (float)x, fy = (float)y;
  float4 stack = make_float4(0.f, 0.f, 0.f, 0.f);
  const float c0 = (1.0f / 512.0f) - 1.0f;   // xs = x/256 + c0
#pragma unroll 1
  for (int i = 0; i < NPARTS; i++) {
    float T0 = th[i * 6 + 0], T1 = th[i * 6 + 1], T2 = th[i * 6 + 2];
    float T3 = th[i * 6 + 3], T4 = th[i * 6 + 4], T5 = th[i * 6 + 5];
    // ix = 256*gx + 255.5, gx = T0*(x/256+c0) + T1*(y/256+c0) + T2
    float Cx = 256.0f * ((T0 + T1) * c0 + T2) + 255.5f;
    float Cy = 256.0f * ((T3 + T4) * c0 + T5) + 255.5f;
    float ix = T0 * fx + T1 * fy + Cx;
    float iy = T3 * fx + T4 * fy + Cy;
    float x0 = floorf(ix), y0 = floorf(iy);
    float wx = ix - x0, wy = iy - y0;
    int x0i = min(max((int)x0, 0), 511);
    int x1i = min(max((int)x0 + 1, 0), 511);
    int y0i = min(max((int)y0, 0), 511);
    int y1i = min(max((int)y0 + 1, 0), 511);
    const float4* img = img0 + (size_t)(i + 1) * 512 * 512;
    float4 v00 = img[y0i * 512 + x0i];
    float4 v01 = img[y0i * 512 + x1i];
    float4 v10 = img[y1i * 512 + x0i];
    float4 v11 = img[y1i * 512 + x1i];
    float w00 = (1.f - wx) * (1.f - wy), w01 = wx * (1.f - wy);
    float w10 = (1.f - wx) * wy, w11 = wx * wy;
    float4 val;
    val.x = v00.x * w00 + v01.x * w01 + v10.x * w10 + v11.x * w11;
    val.y = v00.y * w00 + v01.y * w01 + v10.y * w10 + v11.y * w11;
    val.z = v00.z * w00 + v01.z * w01 + v10.z * w10 + v11.z * w11;
    val.w = v00.w * w00 + v01.w * w01 + v10.w * w10 + v11.w * w11;
    if (i == 0) {
      stack = val;
    } else {
      float a = fminf(fmaxf(val.w, 0.0f), 1.0f);
      stack.x = fminf(fmaxf(stack.x - 2.f * a, -1.f), 1.f);
      stack.y = fminf(fmaxf(stack.y - 2.f * a, -1.f), 1.f);
      stack.z = fminf(fmaxf(stack.z - 2.f * a, -1.f), 1.f);
      stack.w = fminf(fmaxf(stack.w - 2.f * a, -1.f), 1.f);
      stack.x = fminf(fmaxf(stack.x + val.x + 1.f, -1.f), 1.f);
      stack.y = fminf(fmaxf(stack.y + val.y + 1.f, -1.f), 1.f);
      stack.z = fminf(fmaxf(stack.z + val.z + 1.f, -1.f), 1.f);
      stack.w = fminf(fmaxf(stack.w + val.w + 1.f, -1.f), 1.f);
    }
  }
  size_t obase = (size_t)b * 4 * 262144 + (size_t)y * 512 + x;
  out[obase] = stack.x;
  out[obase + 262144] = stack.y;
  out[obase + 2 * 262144] = stack.z;
  out[obase + 3 * 262144] = stack.w;
}

extern "C" void kernel_launch(void* const* d_in, const int* in_sizes, int n_in,
                              void* d_out, int out_size, void* d_ws, size_t ws_size,
                              hipStream_t stream) {
  const float4* x4 = (const float4*)d_in[0];
  const float* conv1_w = (const float*)d_in[1];
  const float* conv1_b = (const float*)d_in[2];
  const float* conv2_w = (const float*)d_in[3];
  const float* conv2_b = (const float*)d_in[4];
  const float* fc1_w = (const float*)d_in[5];
  const float* fc1_b = (const float*)d_in[6];
  const float* fc2_w = (const float*)d_in[7];
  const float* fc2_b = (const float*)d_in[8];
  const float* fc3_w = (const float*)d_in[9];
  const float* fc3_b = (const float*)d_in[10];
  float* ws = (float*)d_ws;
  float* out = (float*)d_out;

  conv1_kernel<<<dim3(256, 4), 256, 0, stream>>>(x4, conv1_w, conv1_b, ws + OFF_H1);
  conv2_kernel<<<dim3(64, 4), 256, 0, stream>>>(ws + OFF_H1, conv2_w, conv2_b, ws + OFF_H2);
  fc1_kernel<<<dim3(32, 8), 256, 0, stream>>>(ws + OFF_H2, fc1_w, ws + OFF_PART);
  head_kernel<<<1, 256, 0, stream>>>(ws + OFF_PART, fc1_b, fc2_w, fc2_b, fc3_w, fc3_b,
                                     ws + OFF_THETA, out + 4194304);
  warp_kernel<<<4096, 256, 0, stream>>>(x4, ws + OFF_THETA, out);
}